// Round 3
// baseline (282.410 us; speedup 1.0000x reference)
//
#include <hip/hip_runtime.h>
#include <hip/hip_bf16.h>
#include <math.h>

// Problem constants
#define B_     16
#define S_     2048
#define H_     1024
#define NS_    64
#define NC_    4096
#define NROWS  1024   // B_*NS_

#define SCALE_ 30.0f
#define COS_M_ 0.8775825618903728f     // cos(0.5)
#define SIN_M_ 0.479425538604203f      // sin(0.5)
#define TH_    (-0.8775825618903728f)  // cos(pi-0.5)
#define MM_    0.2397127693021015f     // sin(pi-0.5)*0.5
#define LN_EPS_ 1e-7f

// ---------- helpers ----------

__device__ __forceinline__ unsigned short f2bf(float f) {
    union { float f; unsigned int u; } v; v.f = f;
    unsigned int r = v.u + 0x7fffu + ((v.u >> 16) & 1u);   // RNE
    return (unsigned short)(r >> 16);
}

__device__ __forceinline__ float block_sum(float v) {
    __shared__ float sb[4];
    #pragma unroll
    for (int off = 32; off > 0; off >>= 1) v += __shfl_down(v, off, 64);
    if ((threadIdx.x & 63) == 0) sb[threadIdx.x >> 6] = v;
    __syncthreads();
    float r = sb[0] + sb[1] + sb[2] + sb[3];
    __syncthreads();
    return r;
}

// async global->LDS, 16 bytes per lane. LDS dest must be waveBase + lane*16.
__device__ __forceinline__ void gload16(const void* g, void* l) {
    __builtin_amdgcn_global_load_lds(
        (const __attribute__((address_space(1))) unsigned int*)g,
        (__attribute__((address_space(3))) unsigned int*)l,
        16, 0, 0);
}

typedef short bf16x8 __attribute__((ext_vector_type(8)));
typedef float f32x4  __attribute__((ext_vector_type(4)));

// ---------- K1: fused prep. blocks [0,1024): span mean+LN+l2norm.
//                           blocks [1024,5120): l2norm arc_weight rows. ----------
__global__ __launch_bounds__(256) void prep_kernel(
    const float* __restrict__ enc,      // [B,S,H]
    const float* __restrict__ gamma,    // [H]
    const float* __restrict__ beta,     // [H]
    const float* __restrict__ W,        // [NC,H]
    const int*   __restrict__ heads,    // [B,NS]
    const int*   __restrict__ tails,    // [B,NS]
    unsigned short* __restrict__ embn,  // [NROWS,H] bf16
    unsigned short* __restrict__ Wn,    // [NC,H] bf16
    unsigned int* __restrict__ counter) // ticket for gemm last-block
{
    const int tid = threadIdx.x;
    if (blockIdx.x >= NROWS) {
        // ---- wnorm path ----
        const int row = blockIdx.x - NROWS;
        float4 x = ((const float4*)(W + (size_t)row * H_))[tid];
        float ss = block_sum(x.x*x.x + x.y*x.y + x.z*x.z + x.w*x.w);
        float invn = 1.0f / fmaxf(sqrtf(ss), 1e-12f);
        ushort4 o;
        o.x = f2bf(x.x * invn); o.y = f2bf(x.y * invn);
        o.z = f2bf(x.z * invn); o.w = f2bf(x.w * invn);
        *(ushort4*)(Wn + (size_t)row * H_ + tid * 4) = o;
        return;
    }
    if (blockIdx.x == 0 && tid == 0) *counter = 0u;   // ws is poisoned 0xAA each call
    // ---- span path ----
    const int span = blockIdx.x;              // 0..1023, row-major over [B,NS]
    const int b    = span >> 6;
    const int head = heads[span];
    const int tail = tails[span];
    const int cnt  = tail - head;

    const float4* base = (const float4*)(enc + ((size_t)b * S_ + head) * H_);
    float4 a; a.x = 0.f; a.y = 0.f; a.z = 0.f; a.w = 0.f;
    for (int s = 0; s < cnt; ++s) {
        float4 x = base[s * (H_ / 4) + tid];
        a.x += x.x; a.y += x.y; a.z += x.z; a.w += x.w;
    }
    const float inv = 1.0f / (float)cnt;
    float v0 = a.x * inv, v1 = a.y * inv, v2 = a.z * inv, v3 = a.w * inv;

    float mu = block_sum(v0 + v1 + v2 + v3) * (1.0f / H_);
    float d0 = v0 - mu, d1 = v1 - mu, d2 = v2 - mu, d3 = v3 - mu;
    float var = block_sum(d0*d0 + d1*d1 + d2*d2 + d3*d3) * (1.0f / H_);
    float rstd = rsqrtf(var + LN_EPS_);

    const int h = tid * 4;
    float y0 = d0 * rstd * gamma[h+0] + beta[h+0];
    float y1 = d1 * rstd * gamma[h+1] + beta[h+1];
    float y2 = d2 * rstd * gamma[h+2] + beta[h+2];
    float y3 = d3 * rstd * gamma[h+3] + beta[h+3];

    float ss = block_sum(y0*y0 + y1*y1 + y2*y2 + y3*y3);
    float invn = 1.0f / fmaxf(sqrtf(ss), 1e-12f);

    ushort4 o;
    o.x = f2bf(y0 * invn); o.y = f2bf(y1 * invn);
    o.z = f2bf(y2 * invn); o.w = f2bf(y3 * invn);
    *(ushort4*)(embn + (size_t)span * H_ + h) = o;
}

// ---------- K2: cosine GEMM (NT bf16 MFMA) + ArcFace + softmax partials
//               + last-block merge -> scalar mean NLL ----------
// M=1024, N=4096, K=1024. Tile 64(M)x128(N), BK=64 -> 16 barrier iters.
// 1D grid 512; bx=id>>5, by=id&31 so each XCD (id%8 round-robin heuristic)
// touches only 4 B-tiles (1MB) + A (2MB) = 3MB (fits its 4MB L2).
// LDS is XOR-swizzled via the GLOBAL fetch address (global_load_lds pins the
// LDS addr to waveBase+lane*16; the per-lane global source is free), so
// ds_read_b128 fragment reads are conflict-free at row-stride 128B.
__global__ __launch_bounds__(256) void gemm_arc_kernel(
    const unsigned short* __restrict__ A,    // [1024,1024] bf16
    const unsigned short* __restrict__ Bw,   // [4096,1024] bf16
    const int*   __restrict__ labels,        // [NROWS]
    float* __restrict__ pmax,                // [32][NROWS]
    float* __restrict__ psum,                // [32][NROWS]
    float* __restrict__ labval,              // [NROWS]
    unsigned int* __restrict__ counter,
    float* __restrict__ out)
{
    __shared__ short As[64 * 64];    // 8 KB
    __shared__ short Bs[128 * 64];   // 16 KB
    __shared__ float red_m[2][64];
    __shared__ float red_s[2][64];
    __shared__ unsigned int s_tkt;

    const int id   = blockIdx.x;
    const int bx   = id >> 5;        // 0..15 (M)
    const int by   = id & 31;        // 0..31 (N)
    const int m0   = bx * 64;
    const int n0   = by * 128;
    const int tid  = threadIdx.x;
    const int lane = tid & 63;
    const int w    = tid >> 6;
    const int wm   = (w & 1) * 32;   // wave M-offset
    const int wn   = (w >> 1) * 64;  // wave N-offset
    const int lrow = lane & 15;
    const int q    = lane >> 4;

    f32x4 acc[2][4];
    #pragma unroll
    for (int i = 0; i < 2; ++i)
        #pragma unroll
        for (int j = 0; j < 4; ++j)
            acc[i][j] = (f32x4){0.f, 0.f, 0.f, 0.f};

    for (int k0 = 0; k0 < 1024; k0 += 64) {
        __syncthreads();
        // stage A: 512 16B-granules; LDS slot c holds global granule (c&7)^(row&7)
        #pragma unroll
        for (int p = 0; p < 2; ++p) {
            const int c   = p * 256 + tid;
            const int row = c >> 3;
            const int g   = (c & 7) ^ (row & 7);
            gload16(A + ((size_t)(m0 + row) << 10) + k0 + g * 8, &As[c * 8]);
        }
        // stage B: 1024 granules
        #pragma unroll
        for (int p = 0; p < 4; ++p) {
            const int c   = p * 256 + tid;
            const int row = c >> 3;
            const int g   = (c & 7) ^ (row & 7);
            gload16(Bw + ((size_t)(n0 + row) << 10) + k0 + g * 8, &Bs[c * 8]);
        }
        __syncthreads();

        bf16x8 af[2][2], bfr[2][4];
        #pragma unroll
        for (int ks = 0; ks < 2; ++ks) {
            #pragma unroll
            for (int i = 0; i < 2; ++i) {
                const int r   = wm + i * 16 + lrow;
                const int pos = (ks * 4 + q) ^ (r & 7);
                af[ks][i] = *(const bf16x8*)(&As[r * 64 + pos * 8]);
            }
            #pragma unroll
            for (int j = 0; j < 4; ++j) {
                const int r   = wn + j * 16 + lrow;
                const int pos = (ks * 4 + q) ^ (r & 7);
                bfr[ks][j] = *(const bf16x8*)(&Bs[r * 64 + pos * 8]);
            }
        }
        #pragma unroll
        for (int ks = 0; ks < 2; ++ks)
            #pragma unroll
            for (int i = 0; i < 2; ++i)
                #pragma unroll
                for (int j = 0; j < 4; ++j)
                    acc[i][j] = __builtin_amdgcn_mfma_f32_16x16x32_bf16(
                        af[ks][i], bfr[ks][j], acc[i][j], 0, 0, 0);
    }

    // ---- fused ArcFace + per-row softmax partials ----
    // C/D layout: col = lane&15, row = (lane>>4)*4 + reg  [m89/m91]
    #pragma unroll
    for (int i = 0; i < 2; ++i) {
        #pragma unroll
        for (int r2 = 0; r2 < 4; ++r2) {
            const int rloc = wm + i * 16 + q * 4 + r2;
            const int grow = m0 + rloc;
            const int lab  = labels[grow];
            float lg[4];
            float lm = -1e30f;
            #pragma unroll
            for (int j = 0; j < 4; ++j) {
                float c = acc[i][j][r2];
                const int gcol = n0 + wn + j * 16 + lrow;
                float logit = c * SCALE_;
                if (gcol == lab) {
                    float sine = sqrtf(fmaxf(1.0f - c * c, 0.0f));
                    float phi  = c * COS_M_ - sine * SIN_M_;
                    float pl   = (c > TH_) ? phi : (c - MM_);
                    logit = pl * SCALE_;
                    labval[grow] = logit;
                }
                lg[j] = logit;
                lm = fmaxf(lm, logit);
            }
            float ls = 0.f;
            #pragma unroll
            for (int j = 0; j < 4; ++j) ls += expf(lg[j] - lm);
            #pragma unroll
            for (int d = 1; d < 16; d <<= 1) {
                float om = __shfl_xor(lm, d, 64);
                float os = __shfl_xor(ls, d, 64);
                float nm = fmaxf(lm, om);
                ls = ls * expf(lm - nm) + os * expf(om - nm);
                lm = nm;
            }
            if (lrow == 0) { red_m[w >> 1][rloc] = lm; red_s[w >> 1][rloc] = ls; }
        }
    }
    __syncthreads();
    if (tid < 64) {
        float ma = red_m[0][tid], sa = red_s[0][tid];
        float mb = red_m[1][tid], sb = red_s[1][tid];
        float M = fmaxf(ma, mb);
        float S = sa * expf(ma - M) + sb * expf(mb - M);
        pmax[(size_t)by * NROWS + m0 + tid] = M;
        psum[(size_t)by * NROWS + m0 + tid] = S;
    }

    // ---- last-block finalize (ticket pattern) ----
    __threadfence();                 // release: every thread's global writes
    __syncthreads();                 // all fences in this block retired
    if (tid == 0) s_tkt = atomicAdd(counter, 1u);
    __syncthreads();
    if (s_tkt != 511u) return;
    __threadfence();                 // acquire: invalidate stale cache lines

    float local = 0.f;
    for (int rr = tid; rr < NROWS; rr += 256) {
        float m = pmax[rr], s = psum[rr];
        #pragma unroll 4
        for (int nbk = 1; nbk < 32; ++nbk) {
            float om = pmax[(size_t)nbk * NROWS + rr];
            float os = psum[(size_t)nbk * NROWS + rr];
            float nm = fmaxf(m, om);
            s = s * expf(m - nm) + os * expf(om - nm);
            m = nm;
        }
        local += logf(s) + m - labval[rr];
    }
    float tot = block_sum(local);
    if (tid == 0) out[0] = tot * (1.0f / NROWS);
}

// ---------- launch ----------
extern "C" void kernel_launch(void* const* d_in, const int* in_sizes, int n_in,
                              void* d_out, int out_size, void* d_ws, size_t ws_size,
                              hipStream_t stream) {
    const float* enc    = (const float*)d_in[0];
    const float* gamma  = (const float*)d_in[1];
    const float* beta   = (const float*)d_in[2];
    const float* W      = (const float*)d_in[3];
    const int*   heads  = (const int*)d_in[4];
    const int*   tails  = (const int*)d_in[5];
    const int*   labels = (const int*)d_in[6];
    float* out = (float*)d_out;

    char* ws = (char*)d_ws;
    unsigned short* embn    = (unsigned short*)(ws);                  // 2 MB
    unsigned short* Wn      = (unsigned short*)(ws + (2u  << 20));    // 8 MB
    float*          pmax    = (float*)        (ws + (10u << 20));     // 128 KB
    float*          psum    = (float*)        (ws + (10u << 20) + (128u << 10));
    float*          labval  = (float*)        (ws + (10u << 20) + (256u << 10));
    unsigned int*   counter = (unsigned int*) (ws + (10u << 20) + (260u << 10));

    prep_kernel<<<NROWS + NC_, 256, 0, stream>>>(enc, gamma, beta, W, heads, tails,
                                                 embn, Wn, counter);
    gemm_arc_kernel<<<512, 256, 0, stream>>>(embn, Wn, labels, pmax, psum, labval,
                                             counter, out);
}

// Round 4
// 240.970 us; speedup vs baseline: 1.1720x; 1.1720x over previous
//
#include <hip/hip_runtime.h>
#include <hip/hip_bf16.h>
#include <math.h>

// Problem constants
#define B_     16
#define S_     2048
#define H_     1024
#define NS_    64
#define NC_    4096
#define NROWS  1024   // B_*NS_

#define SCALE_ 30.0f
#define COS_M_ 0.8775825618903728f     // cos(0.5)
#define SIN_M_ 0.479425538604203f      // sin(0.5)
#define TH_    (-0.8775825618903728f)  // cos(pi-0.5)
#define MM_    0.2397127693021015f     // sin(pi-0.5)*0.5
#define LN_EPS_ 1e-7f

// ---------- helpers ----------

__device__ __forceinline__ unsigned short f2bf(float f) {
    union { float f; unsigned int u; } v; v.f = f;
    unsigned int r = v.u + 0x7fffu + ((v.u >> 16) & 1u);   // RNE
    return (unsigned short)(r >> 16);
}

__device__ __forceinline__ float block_sum(float v) {
    __shared__ float sb[4];
    #pragma unroll
    for (int off = 32; off > 0; off >>= 1) v += __shfl_down(v, off, 64);
    if ((threadIdx.x & 63) == 0) sb[threadIdx.x >> 6] = v;
    __syncthreads();
    float r = sb[0] + sb[1] + sb[2] + sb[3];
    __syncthreads();
    return r;
}

// async global->LDS, 16 bytes per lane. LDS dest must be waveBase + lane*16.
// Global per-lane addresses MUST follow the m97 monotonic pattern (4 lanes per
// 64B row segment) — the R3 XOR-permuted addresses stalled the DMA ~25x.
__device__ __forceinline__ void gload16(const void* g, void* l) {
    __builtin_amdgcn_global_load_lds(
        (const __attribute__((address_space(1))) unsigned int*)g,
        (__attribute__((address_space(3))) unsigned int*)l,
        16, 0, 0);
}

typedef short bf16x8 __attribute__((ext_vector_type(8)));
typedef float f32x4  __attribute__((ext_vector_type(4)));

// ---------- K1: fused prep. blocks [0,1024): span mean+LN+l2norm.
//                           blocks [1024,5120): l2norm arc_weight rows. ----------
__global__ __launch_bounds__(256) void prep_kernel(
    const float* __restrict__ enc,      // [B,S,H]
    const float* __restrict__ gamma,    // [H]
    const float* __restrict__ beta,     // [H]
    const float* __restrict__ W,        // [NC,H]
    const int*   __restrict__ heads,    // [B,NS]
    const int*   __restrict__ tails,    // [B,NS]
    unsigned short* __restrict__ embn,  // [NROWS,H] bf16
    unsigned short* __restrict__ Wn)    // [NC,H] bf16
{
    const int tid = threadIdx.x;
    if (blockIdx.x >= NROWS) {
        // ---- wnorm path ----
        const int row = blockIdx.x - NROWS;
        float4 x = ((const float4*)(W + (size_t)row * H_))[tid];
        float ss = block_sum(x.x*x.x + x.y*x.y + x.z*x.z + x.w*x.w);
        float invn = 1.0f / fmaxf(sqrtf(ss), 1e-12f);
        ushort4 o;
        o.x = f2bf(x.x * invn); o.y = f2bf(x.y * invn);
        o.z = f2bf(x.z * invn); o.w = f2bf(x.w * invn);
        *(ushort4*)(Wn + (size_t)row * H_ + tid * 4) = o;
        return;
    }
    // ---- span path ----
    const int span = blockIdx.x;              // 0..1023, row-major over [B,NS]
    const int b    = span >> 6;
    const int head = heads[span];
    const int tail = tails[span];
    const int cnt  = tail - head;

    const float4* base = (const float4*)(enc + ((size_t)b * S_ + head) * H_);
    float4 a0; a0.x = 0.f; a0.y = 0.f; a0.z = 0.f; a0.w = 0.f;
    float4 a1 = a0;
    int s = 0;
    for (; s + 2 <= cnt; s += 2) {            // 2 independent streams for MLP
        float4 x = base[(s    ) * (H_ / 4) + tid];
        float4 y = base[(s + 1) * (H_ / 4) + tid];
        a0.x += x.x; a0.y += x.y; a0.z += x.z; a0.w += x.w;
        a1.x += y.x; a1.y += y.y; a1.z += y.z; a1.w += y.w;
    }
    if (s < cnt) {
        float4 x = base[s * (H_ / 4) + tid];
        a0.x += x.x; a0.y += x.y; a0.z += x.z; a0.w += x.w;
    }
    const float inv = 1.0f / (float)cnt;
    float v0 = (a0.x + a1.x) * inv, v1 = (a0.y + a1.y) * inv;
    float v2 = (a0.z + a1.z) * inv, v3 = (a0.w + a1.w) * inv;

    float mu = block_sum(v0 + v1 + v2 + v3) * (1.0f / H_);
    float d0 = v0 - mu, d1 = v1 - mu, d2 = v2 - mu, d3 = v3 - mu;
    float var = block_sum(d0*d0 + d1*d1 + d2*d2 + d3*d3) * (1.0f / H_);
    float rstd = rsqrtf(var + LN_EPS_);

    const int h = tid * 4;
    float y0 = d0 * rstd * gamma[h+0] + beta[h+0];
    float y1 = d1 * rstd * gamma[h+1] + beta[h+1];
    float y2 = d2 * rstd * gamma[h+2] + beta[h+2];
    float y3 = d3 * rstd * gamma[h+3] + beta[h+3];

    float ss = block_sum(y0*y0 + y1*y1 + y2*y2 + y3*y3);
    float invn = 1.0f / fmaxf(sqrtf(ss), 1e-12f);

    ushort4 o;
    o.x = f2bf(y0 * invn); o.y = f2bf(y1 * invn);
    o.z = f2bf(y2 * invn); o.w = f2bf(y3 * invn);
    *(ushort4*)(embn + (size_t)span * H_ + h) = o;
}

// ---------- K2: cosine GEMM (NT bf16 MFMA, m97/R1 structure) + fused
//               ArcFace + per-row softmax partials ----------
// M=1024, N=4096, K=1024. 128x128 tile, BK=32, grid (8,32)=256 blocks.
__global__ __launch_bounds__(256, 1) void gemm_arc_kernel(
    const unsigned short* __restrict__ A,    // [1024,1024] bf16
    const unsigned short* __restrict__ Bw,   // [4096,1024] bf16
    const int*   __restrict__ labels,        // [NROWS]
    float* __restrict__ pmax,                // [32][NROWS]
    float* __restrict__ psum,                // [32][NROWS]
    float* __restrict__ labval)              // [NROWS]
{
    __shared__ short As[128 * 32];   // unpadded: global_load_lds lane-contig
    __shared__ short Bs[128 * 32];
    __shared__ float red_m[2][128];
    __shared__ float red_s[2][128];

    const int m0   = blockIdx.x * 128;
    const int n0   = blockIdx.y * 128;
    const int nb   = blockIdx.y;
    const int tid  = threadIdx.x;
    const int lane = tid & 63;
    const int w    = tid >> 6;
    const int wm   = (w & 1) * 64;
    const int wn   = (w >> 1) * 64;
    const int lrow = lane & 15;
    const int q    = lane >> 4;

    const int rowA   = tid >> 2;        // 0..63
    const int kchunk = (tid & 3) * 8;   // bf16 elems within K-slab

    f32x4 acc[4][4];
    #pragma unroll
    for (int i = 0; i < 4; ++i)
        #pragma unroll
        for (int j = 0; j < 4; ++j)
            acc[i][j] = (f32x4){0.f, 0.f, 0.f, 0.f};

    for (int k0 = 0; k0 < 1024; k0 += 32) {
        __syncthreads();
        #pragma unroll
        for (int t = 0; t < 2; ++t) {
            const int r = t * 64 + rowA;
            gload16(A  + ((size_t)(m0 + r) << 10) + k0 + kchunk, &As[r * 32 + kchunk]);
            gload16(Bw + ((size_t)(n0 + r) << 10) + k0 + kchunk, &Bs[r * 32 + kchunk]);
        }
        __syncthreads();

        bf16x8 af[4], bfr[4];
        #pragma unroll
        for (int i = 0; i < 4; ++i)
            af[i] = *(const bf16x8*)(&As[(wm + i * 16 + lrow) * 32 + q * 8]);
        #pragma unroll
        for (int j = 0; j < 4; ++j)
            bfr[j] = *(const bf16x8*)(&Bs[(wn + j * 16 + lrow) * 32 + q * 8]);

        #pragma unroll
        for (int i = 0; i < 4; ++i)
            #pragma unroll
            for (int j = 0; j < 4; ++j)
                acc[i][j] = __builtin_amdgcn_mfma_f32_16x16x32_bf16(af[i], bfr[j], acc[i][j], 0, 0, 0);
    }

    // ---- fused ArcFace + per-row softmax partials over this block's 128 cols ----
    // C/D layout: col = lane&15, row = (lane>>4)*4 + reg  [m89/m91]
    #pragma unroll
    for (int i = 0; i < 4; ++i) {
        #pragma unroll
        for (int r2 = 0; r2 < 4; ++r2) {
            const int rloc = wm + i * 16 + q * 4 + r2;   // 0..127
            const int grow = m0 + rloc;
            const int lab  = labels[grow];
            float lg[4];
            float lm = -1e30f;
            #pragma unroll
            for (int j = 0; j < 4; ++j) {
                float c = acc[i][j][r2];
                const int gcol = n0 + wn + j * 16 + lrow;
                float logit = c * SCALE_;
                if (gcol == lab) {
                    float sine = sqrtf(fmaxf(1.0f - c * c, 0.0f));
                    float phi  = c * COS_M_ - sine * SIN_M_;
                    float pl   = (c > TH_) ? phi : (c - MM_);
                    logit = pl * SCALE_;
                    labval[grow] = logit;
                }
                lg[j] = logit;
                lm = fmaxf(lm, logit);
            }
            float ls = 0.f;
            #pragma unroll
            for (int j = 0; j < 4; ++j) ls += expf(lg[j] - lm);
            // reduce across the 16 lrow lanes (same q) -> this wave's 64 cols
            #pragma unroll
            for (int d = 1; d < 16; d <<= 1) {
                float om = __shfl_xor(lm, d, 64);
                float os = __shfl_xor(ls, d, 64);
                float nm = fmaxf(lm, om);
                ls = ls * expf(lm - nm) + os * expf(om - nm);
                lm = nm;
            }
            if (lrow == 0) { red_m[w >> 1][rloc] = lm; red_s[w >> 1][rloc] = ls; }
        }
    }
    __syncthreads();
    if (tid < 128) {
        float ma = red_m[0][tid], sa = red_s[0][tid];
        float mb = red_m[1][tid], sb = red_s[1][tid];
        float M = fmaxf(ma, mb);
        float S = sa * expf(ma - M) + sb * expf(mb - M);
        pmax[(size_t)nb * NROWS + m0 + tid] = M;
        psum[(size_t)nb * NROWS + m0 + tid] = S;
    }
}

// ---------- K3: merge partials, NLL per row, mean ----------
__global__ __launch_bounds__(1024) void finalize_kernel(
    const float* __restrict__ pmax,     // [32][NROWS]
    const float* __restrict__ psum,
    const float* __restrict__ labval,   // [NROWS]
    float* __restrict__ out)
{
    __shared__ float sb[16];
    const int row = threadIdx.x;        // 0..1023
    float m = pmax[row], s = psum[row];
    #pragma unroll 4
    for (int nbk = 1; nbk < 32; ++nbk) {
        float om = pmax[nbk * NROWS + row];
        float os = psum[nbk * NROWS + row];
        float nm = fmaxf(m, om);
        s = s * expf(m - nm) + os * expf(om - nm);
        m = nm;
    }
    float nll = logf(s) + m - labval[row];
    #pragma unroll
    for (int off = 32; off > 0; off >>= 1) nll += __shfl_down(nll, off, 64);
    if ((row & 63) == 0) sb[row >> 6] = nll;
    __syncthreads();
    if (row < 64) {
        float v = (row < 16) ? sb[row] : 0.f;
        #pragma unroll
        for (int off = 8; off > 0; off >>= 1) v += __shfl_down(v, off, 64);
        if (row == 0) out[0] = v * (1.0f / NROWS);
    }
}

// ---------- launch ----------
extern "C" void kernel_launch(void* const* d_in, const int* in_sizes, int n_in,
                              void* d_out, int out_size, void* d_ws, size_t ws_size,
                              hipStream_t stream) {
    const float* enc    = (const float*)d_in[0];
    const float* gamma  = (const float*)d_in[1];
    const float* beta   = (const float*)d_in[2];
    const float* W      = (const float*)d_in[3];
    const int*   heads  = (const int*)d_in[4];
    const int*   tails  = (const int*)d_in[5];
    const int*   labels = (const int*)d_in[6];
    float* out = (float*)d_out;

    char* ws = (char*)d_ws;
    unsigned short* embn   = (unsigned short*)(ws);                  // 2 MB
    unsigned short* Wn     = (unsigned short*)(ws + (2u  << 20));    // 8 MB
    float*          pmax   = (float*)        (ws + (10u << 20));     // 128 KB
    float*          psum   = (float*)        (ws + (10u << 20) + (128u << 10));
    float*          labval = (float*)        (ws + (10u << 20) + (256u << 10));

    prep_kernel<<<NROWS + NC_, 256, 0, stream>>>(enc, gamma, beta, W, heads, tails,
                                                 embn, Wn);
    dim3 g2(NROWS / 128, NC_ / 128);
    gemm_arc_kernel<<<g2, 256, 0, stream>>>(embn, Wn, labels, pmax, psum, labval);
    finalize_kernel<<<1, 1024, 0, stream>>>(pmax, psum, labval, out);
}

// Round 5
// 234.666 us; speedup vs baseline: 1.2035x; 1.0269x over previous
//
#include <hip/hip_runtime.h>
#include <hip/hip_bf16.h>
#include <math.h>

// Problem constants
#define B_     16
#define S_     2048
#define H_     1024
#define NS_    64
#define NC_    4096
#define NROWS  1024   // B_*NS_

#define SCALE_ 30.0f
#define COS_M_ 0.8775825618903728f     // cos(0.5)
#define SIN_M_ 0.479425538604203f      // sin(0.5)
#define TH_    (-0.8775825618903728f)  // cos(pi-0.5)
#define MM_    0.2397127693021015f     // sin(pi-0.5)*0.5
#define LN_EPS_ 1e-7f

// ---------- helpers ----------

__device__ __forceinline__ unsigned short f2bf(float f) {
    union { float f; unsigned int u; } v; v.f = f;
    unsigned int r = v.u + 0x7fffu + ((v.u >> 16) & 1u);   // RNE
    return (unsigned short)(r >> 16);
}

__device__ __forceinline__ float block_sum(float v) {
    __shared__ float sb[4];
    #pragma unroll
    for (int off = 32; off > 0; off >>= 1) v += __shfl_down(v, off, 64);
    if ((threadIdx.x & 63) == 0) sb[threadIdx.x >> 6] = v;
    __syncthreads();
    float r = sb[0] + sb[1] + sb[2] + sb[3];
    __syncthreads();
    return r;
}

// async global->LDS, 16 bytes per lane. LDS dest must be waveBase + lane*16.
// Global per-lane addresses MUST be monotonic m97-style (4 lanes per 64B row
// segment) — R3's XOR-permuted addresses stalled the DMA ~25x.
__device__ __forceinline__ void gload16(const void* g, void* l) {
    __builtin_amdgcn_global_load_lds(
        (const __attribute__((address_space(1))) unsigned int*)g,
        (__attribute__((address_space(3))) unsigned int*)l,
        16, 0, 0);
}

typedef short bf16x8 __attribute__((ext_vector_type(8)));
typedef float f32x4  __attribute__((ext_vector_type(4)));

// ---------- K1: fused prep. blocks [0,1024): span mean+LN+l2norm.
//                           blocks [1024,5120): l2norm arc_weight rows. ----------
__global__ __launch_bounds__(256) void prep_kernel(
    const float* __restrict__ enc,      // [B,S,H]
    const float* __restrict__ gamma,    // [H]
    const float* __restrict__ beta,     // [H]
    const float* __restrict__ W,        // [NC,H]
    const int*   __restrict__ heads,    // [B,NS]
    const int*   __restrict__ tails,    // [B,NS]
    unsigned short* __restrict__ embn,  // [NROWS,H] bf16
    unsigned short* __restrict__ Wn)    // [NC,H] bf16
{
    const int tid = threadIdx.x;
    if (blockIdx.x >= NROWS) {
        // ---- wnorm path ----
        const int row = blockIdx.x - NROWS;
        float4 x = ((const float4*)(W + (size_t)row * H_))[tid];
        float ss = block_sum(x.x*x.x + x.y*x.y + x.z*x.z + x.w*x.w);
        float invn = 1.0f / fmaxf(sqrtf(ss), 1e-12f);
        ushort4 o;
        o.x = f2bf(x.x * invn); o.y = f2bf(x.y * invn);
        o.z = f2bf(x.z * invn); o.w = f2bf(x.w * invn);
        *(ushort4*)(Wn + (size_t)row * H_ + tid * 4) = o;
        return;
    }
    // ---- span path ----
    const int span = blockIdx.x;              // 0..1023, row-major over [B,NS]
    const int b    = span >> 6;
    const int head = heads[span];
    const int tail = tails[span];
    const int cnt  = tail - head;

    const float4* base = (const float4*)(enc + ((size_t)b * S_ + head) * H_);
    float4 a0; a0.x = 0.f; a0.y = 0.f; a0.z = 0.f; a0.w = 0.f;
    float4 a1 = a0;
    int s = 0;
    for (; s + 2 <= cnt; s += 2) {            // 2 independent streams for MLP
        float4 x = base[(s    ) * (H_ / 4) + tid];
        float4 y = base[(s + 1) * (H_ / 4) + tid];
        a0.x += x.x; a0.y += x.y; a0.z += x.z; a0.w += x.w;
        a1.x += y.x; a1.y += y.y; a1.z += y.z; a1.w += y.w;
    }
    if (s < cnt) {
        float4 x = base[s * (H_ / 4) + tid];
        a0.x += x.x; a0.y += x.y; a0.z += x.z; a0.w += x.w;
    }
    const float inv = 1.0f / (float)cnt;
    float v0 = (a0.x + a1.x) * inv, v1 = (a0.y + a1.y) * inv;
    float v2 = (a0.z + a1.z) * inv, v3 = (a0.w + a1.w) * inv;

    float mu = block_sum(v0 + v1 + v2 + v3) * (1.0f / H_);
    float d0 = v0 - mu, d1 = v1 - mu, d2 = v2 - mu, d3 = v3 - mu;
    float var = block_sum(d0*d0 + d1*d1 + d2*d2 + d3*d3) * (1.0f / H_);
    float rstd = rsqrtf(var + LN_EPS_);

    const int h = tid * 4;
    float y0 = d0 * rstd * gamma[h+0] + beta[h+0];
    float y1 = d1 * rstd * gamma[h+1] + beta[h+1];
    float y2 = d2 * rstd * gamma[h+2] + beta[h+2];
    float y3 = d3 * rstd * gamma[h+3] + beta[h+3];

    float ss = block_sum(y0*y0 + y1*y1 + y2*y2 + y3*y3);
    float invn = 1.0f / fmaxf(sqrtf(ss), 1e-12f);

    ushort4 o;
    o.x = f2bf(y0 * invn); o.y = f2bf(y1 * invn);
    o.z = f2bf(y2 * invn); o.w = f2bf(y3 * invn);
    *(ushort4*)(embn + (size_t)span * H_ + h) = o;
}

// ---------- K2: cosine GEMM (NT bf16 MFMA) + fused ArcFace + softmax partials ----------
// M=1024, N=4096, K=1024. Tile 64(M)x128(N), BK=32 -> grid (16,32)=512 blocks
// = 2 blocks/CU, so a co-resident block computes through the other's
// __syncthreads+vmcnt drain (the 1-block/CU 128x128 grid had zero overlap).
__global__ __launch_bounds__(256) void gemm_arc_kernel(
    const unsigned short* __restrict__ A,    // [1024,1024] bf16
    const unsigned short* __restrict__ Bw,   // [4096,1024] bf16
    const int*   __restrict__ labels,        // [NROWS]
    float* __restrict__ pmax,                // [32][NROWS]
    float* __restrict__ psum,                // [32][NROWS]
    float* __restrict__ labval)              // [NROWS]
{
    __shared__ short As[64 * 32];    // unpadded: global_load_lds lane-contig
    __shared__ short Bs[128 * 32];
    __shared__ float red_m[2][64];
    __shared__ float red_s[2][64];

    const int m0   = blockIdx.x * 64;
    const int n0   = blockIdx.y * 128;
    const int nb   = blockIdx.y;
    const int tid  = threadIdx.x;
    const int lane = tid & 63;
    const int w    = tid >> 6;
    const int wm   = (w & 1) * 32;   // wave M-offset
    const int wn   = (w >> 1) * 64;  // wave N-offset
    const int lrow = lane & 15;
    const int q    = lane >> 4;

    const int rowA   = tid >> 2;        // 0..63
    const int kchunk = (tid & 3) * 8;   // bf16 elems within K-slab

    f32x4 acc[2][4];
    #pragma unroll
    for (int i = 0; i < 2; ++i)
        #pragma unroll
        for (int j = 0; j < 4; ++j)
            acc[i][j] = (f32x4){0.f, 0.f, 0.f, 0.f};

    for (int k0 = 0; k0 < 1024; k0 += 32) {
        __syncthreads();
        gload16(A + ((size_t)(m0 + rowA) << 10) + k0 + kchunk, &As[rowA * 32 + kchunk]);
        #pragma unroll
        for (int t = 0; t < 2; ++t) {
            const int r = t * 64 + rowA;
            gload16(Bw + ((size_t)(n0 + r) << 10) + k0 + kchunk, &Bs[r * 32 + kchunk]);
        }
        __syncthreads();

        bf16x8 af[2], bfr[4];
        #pragma unroll
        for (int i = 0; i < 2; ++i)
            af[i] = *(const bf16x8*)(&As[(wm + i * 16 + lrow) * 32 + q * 8]);
        #pragma unroll
        for (int j = 0; j < 4; ++j)
            bfr[j] = *(const bf16x8*)(&Bs[(wn + j * 16 + lrow) * 32 + q * 8]);

        #pragma unroll
        for (int i = 0; i < 2; ++i)
            #pragma unroll
            for (int j = 0; j < 4; ++j)
                acc[i][j] = __builtin_amdgcn_mfma_f32_16x16x32_bf16(af[i], bfr[j], acc[i][j], 0, 0, 0);
    }

    // ---- fused ArcFace + per-row softmax partials over this block's 128 cols ----
    // C/D layout: col = lane&15, row = (lane>>4)*4 + reg  [m89/m91]
    #pragma unroll
    for (int i = 0; i < 2; ++i) {
        #pragma unroll
        for (int r2 = 0; r2 < 4; ++r2) {
            const int rloc = wm + i * 16 + q * 4 + r2;   // 0..63
            const int grow = m0 + rloc;
            const int lab  = labels[grow];
            float lg[4];
            float lm = -1e30f;
            #pragma unroll
            for (int j = 0; j < 4; ++j) {
                float c = acc[i][j][r2];
                const int gcol = n0 + wn + j * 16 + lrow;
                float logit = c * SCALE_;
                if (gcol == lab) {
                    float sine = sqrtf(fmaxf(1.0f - c * c, 0.0f));
                    float phi  = c * COS_M_ - sine * SIN_M_;
                    float pl   = (c > TH_) ? phi : (c - MM_);
                    logit = pl * SCALE_;
                    labval[grow] = logit;
                }
                lg[j] = logit;
                lm = fmaxf(lm, logit);
            }
            float ls = 0.f;
            #pragma unroll
            for (int j = 0; j < 4; ++j) ls += expf(lg[j] - lm);
            // reduce across the 16 lrow lanes (same q) -> this wave's 64 cols
            #pragma unroll
            for (int d = 1; d < 16; d <<= 1) {
                float om = __shfl_xor(lm, d, 64);
                float os = __shfl_xor(ls, d, 64);
                float nm = fmaxf(lm, om);
                ls = ls * expf(lm - nm) + os * expf(om - nm);
                lm = nm;
            }
            if (lrow == 0) { red_m[w >> 1][rloc] = lm; red_s[w >> 1][rloc] = ls; }
        }
    }
    __syncthreads();
    if (tid < 64) {
        float ma = red_m[0][tid], sa = red_s[0][tid];
        float mb = red_m[1][tid], sb = red_s[1][tid];
        float M = fmaxf(ma, mb);
        float S = sa * expf(ma - M) + sb * expf(mb - M);
        pmax[(size_t)nb * NROWS + m0 + tid] = M;
        psum[(size_t)nb * NROWS + m0 + tid] = S;
    }
}

// ---------- K3: merge partials, NLL per row, mean ----------
__global__ __launch_bounds__(1024) void finalize_kernel(
    const float* __restrict__ pmax,     // [32][NROWS]
    const float* __restrict__ psum,
    const float* __restrict__ labval,   // [NROWS]
    float* __restrict__ out)
{
    __shared__ float sb[16];
    const int row = threadIdx.x;        // 0..1023
    float m = pmax[row], s = psum[row];
    #pragma unroll 4
    for (int nbk = 1; nbk < 32; ++nbk) {
        float om = pmax[nbk * NROWS + row];
        float os = psum[nbk * NROWS + row];
        float nm = fmaxf(m, om);
        s = s * expf(m - nm) + os * expf(om - nm);
        m = nm;
    }
    float nll = logf(s) + m - labval[row];
    #pragma unroll
    for (int off = 32; off > 0; off >>= 1) nll += __shfl_down(nll, off, 64);
    if ((row & 63) == 0) sb[row >> 6] = nll;
    __syncthreads();
    if (row < 64) {
        float v = (row < 16) ? sb[row] : 0.f;
        #pragma unroll
        for (int off = 8; off > 0; off >>= 1) v += __shfl_down(v, off, 64);
        if (row == 0) out[0] = v * (1.0f / NROWS);
    }
}

// ---------- launch ----------
extern "C" void kernel_launch(void* const* d_in, const int* in_sizes, int n_in,
                              void* d_out, int out_size, void* d_ws, size_t ws_size,
                              hipStream_t stream) {
    const float* enc    = (const float*)d_in[0];
    const float* gamma  = (const float*)d_in[1];
    const float* beta   = (const float*)d_in[2];
    const float* W      = (const float*)d_in[3];
    const int*   heads  = (const int*)d_in[4];
    const int*   tails  = (const int*)d_in[5];
    const int*   labels = (const int*)d_in[6];
    float* out = (float*)d_out;

    char* ws = (char*)d_ws;
    unsigned short* embn   = (unsigned short*)(ws);                  // 2 MB
    unsigned short* Wn     = (unsigned short*)(ws + (2u  << 20));    // 8 MB
    float*          pmax   = (float*)        (ws + (10u << 20));     // 128 KB
    float*          psum   = (float*)        (ws + (10u << 20) + (128u << 10));
    float*          labval = (float*)        (ws + (10u << 20) + (256u << 10));

    prep_kernel<<<NROWS + NC_, 256, 0, stream>>>(enc, gamma, beta, W, heads, tails,
                                                 embn, Wn);
    dim3 g2(NROWS / 64, NC_ / 128);
    gemm_arc_kernel<<<g2, 256, 0, stream>>>(embn, Wn, labels, pmax, psum, labval);
    finalize_kernel<<<1, 1024, 0, stream>>>(pmax, psum, labval, out);
}